// Round 18
// baseline (53.926 us; speedup 1.0000x reference)
//
#include <hip/hip_runtime.h>
#include <hip/hip_bf16.h>

#define BIN_ROWS   8
#define MAX_BINS   256
#define OFF_STRIDE 257
#define P1_PTS     1024

typedef unsigned short u16;
typedef unsigned int   u32;

__device__ __forceinline__ bool fit_ok(int HW, int bev_h, int bev_w, int ws_ok) {
    return ws_ok && (HW % P1_PTS == 0) && (bev_h % BIN_ROWS == 0) &&
           (bev_h / BIN_ROWS <= MAX_BINS) && (bev_w <= 1024) && (bev_w % 4 == 0);
}

// Class-E index math (verified R11): single f32 rounding of the EXACT
// quotient a/(0.1*scale) via opaque f64 reciprocal-multiply; f32 add 512,
// rintf (RNE), trunc-to-int.
__device__ __forceinline__ void classE(float px, float pz, double rd,
                                       float half_w, int& xi, int& zi) {
    float xq = (float)((double)(-px) * rd);
    float zq = (float)((double)pz  * rd);
    xi = (int)rintf(__fadd_rn(xq, half_w));
    zi = (int)rintf(zq);
}

// kA: fit -> P1 bin pass (LDS counting sort, coalesced pair writes, NO global
// atomics); unfit -> fallback EMPTY fill.
__global__ __launch_bounds__(256) void kA(const float* __restrict__ labels,
        const float* __restrict__ pc,
        const int* __restrict__ p_bev_h, const int* __restrict__ p_bev_w,
        const int* __restrict__ p_scale, float* __restrict__ out,
        u16* __restrict__ cell16, float* __restrict__ lab32,
        u16* __restrict__ offs16, int n_pts, int out_size, int ws_ok) {
    const int bev_h = *p_bev_h, bev_w = *p_bev_w, scale = *p_scale;
    const int img = bev_h * bev_w;
    const int B = out_size / img;
    const int HW = n_pts / B;
    const float half_w = (float)(bev_w / 2);
    double rd = 1.0 / (0.1 * (double)scale);
    asm volatile("" : "+v"(rd));

    if (fit_ok(HW, bev_h, bev_w, ws_ok)) {
        const int nbins = bev_h / BIN_ROWS;
        const int nblk_pb = HW / P1_PTS;
        const int nblkTot = B * nblk_pb;
        int gblk = blockIdx.x;
        if (gblk >= nblkTot) return;
        int batch = gblk / nblk_pb;
        int r = (gblk - batch * nblk_pb) * P1_PTS + threadIdx.x * 4;

        __shared__ u32 hist[MAX_BINS];
        __shared__ u32 scan[MAX_BINS];
        __shared__ u16 cellL[P1_PTS];
        __shared__ float labL[P1_PTS];

        const float* pcb = pc + (size_t)batch * 3u * (size_t)HW;
        float4 lab = *(const float4*)(labels + (size_t)batch * (size_t)HW + r);
        float4 x0  = *(const float4*)(pcb + r);
        float4 z0  = *(const float4*)(pcb + 2 * (size_t)HW + r);
        float xs[4] = {x0.x, x0.y, x0.z, x0.w};
        float zs[4] = {z0.x, z0.y, z0.z, z0.w};
        float ls[4] = {lab.x, lab.y, lab.z, lab.w};

        int bin[4]; u16 cell[4]; bool val[4];
#pragma unroll
        for (int k = 0; k < 4; ++k) {
            int xi, zi; classE(xs[k], zs[k], rd, half_w, xi, zi);
            val[k]  = (xi >= 0 && xi < bev_w && zi >= 0 && zi < bev_h);
            bin[k]  = val[k] ? (zi >> 3) : 0;
            cell[k] = val[k] ? (u16)((zi & 7) * bev_w + xi) : 0;
        }
        if ((int)threadIdx.x < nbins) hist[threadIdx.x] = 0;
        __syncthreads();
#pragma unroll
        for (int k = 0; k < 4; ++k) if (val[k]) atomicAdd(&hist[bin[k]], 1u);
        __syncthreads();
        // inclusive Hillis-Steele scan over MAX_BINS entries (256 threads)
        u32 v = ((int)threadIdx.x < nbins) ? hist[threadIdx.x] : 0;
        scan[threadIdx.x] = v;
        __syncthreads();
        for (int d = 1; d < MAX_BINS; d <<= 1) {
            u32 t = (threadIdx.x >= (unsigned)d) ? scan[threadIdx.x - d] : 0;
            __syncthreads();
            scan[threadIdx.x] += t;
            __syncthreads();
        }
        if ((int)threadIdx.x < nbins)
            hist[threadIdx.x] = (threadIdx.x == 0) ? 0 : scan[threadIdx.x - 1];
        __syncthreads();
#pragma unroll
        for (int k = 0; k < 4; ++k) if (val[k]) {
            u32 pos = atomicAdd(&hist[bin[k]], 1u);
            cellL[pos] = cell[k];
            labL[pos]  = ls[k];
        }
        __syncthreads();
        u32 total = scan[nbins - 1];
        u16* cg = cell16 + (size_t)gblk * P1_PTS;
        float* lg = lab32 + (size_t)gblk * P1_PTS;
        for (u32 i = threadIdx.x; i < total; i += 256) {
            cg[i] = cellL[i];
            lg[i] = labL[i];
        }
        u16* og = offs16 + (size_t)gblk * OFF_STRIDE;
        for (int j = threadIdx.x; j <= nbins; j += 256)
            og[j] = (u16)((j == 0) ? 0 : scan[j - 1]);
    } else {
        // fallback: fill with EMPTY (R12 form, grid-stride)
        int n4 = out_size >> 2;
        const float4 vv = make_float4(255.f, 255.f, 255.f, 255.f);
        for (int i = blockIdx.x * 256 + threadIdx.x; i < n4;
             i += gridDim.x * 256)
            ((float4*)out)[i] = vv;
    }
}

// kB: fit -> P2 tile pass (LDS tile init 255 + run-gather + LDS scatter +
// coalesced float4 streamout; absorbs the fill); unfit -> fallback direct
// scatter (R12 semantics).
__global__ __launch_bounds__(256) void kB(const float* __restrict__ labels,
        const float* __restrict__ pc,
        const int* __restrict__ p_bev_h, const int* __restrict__ p_bev_w,
        const int* __restrict__ p_scale, float* __restrict__ out,
        const u16* __restrict__ cell16, const float* __restrict__ lab32,
        const u16* __restrict__ offs16, int n_pts, int out_size, int ws_ok) {
    const int bev_h = *p_bev_h, bev_w = *p_bev_w, scale = *p_scale;
    const int img = bev_h * bev_w;
    const int B = out_size / img;
    const int HW = n_pts / B;
    const float half_w = (float)(bev_w / 2);
    double rd = 1.0 / (0.1 * (double)scale);
    asm volatile("" : "+v"(rd));

    if (fit_ok(HW, bev_h, bev_w, ws_ok)) {
        const int nbins = bev_h / BIN_ROWS;
        const int nblk_pb = HW / P1_PTS;
        const int ntiles = B * nbins;
        const int nel = BIN_ROWS * bev_w;
        __shared__ float tile[BIN_ROWS * 1024];
        for (int t = blockIdx.x; t < ntiles; t += gridDim.x) {
            int bt = t / nbins, j = t - bt * nbins;
            for (int i = threadIdx.x; i < nel; i += 256) tile[i] = 255.0f;
            __syncthreads();
            for (int s = threadIdx.x; s < nblk_pb; s += 256) {
                int gblk = bt * nblk_pb + s;
                const u16* og = offs16 + (size_t)gblk * OFF_STRIDE;
                int o0 = og[j], o1 = og[j + 1];
                const u16* cg = cell16 + (size_t)gblk * P1_PTS;
                const float* lg = lab32 + (size_t)gblk * P1_PTS;
                for (int i = o0; i < o1; ++i) tile[cg[i]] = lg[i];
            }
            __syncthreads();
            float4* dst = (float4*)(out + (size_t)bt * img + (size_t)j * nel);
            const float4* src = (const float4*)tile;
            for (int i = threadIdx.x; i < (nel >> 2); i += 256) dst[i] = src[i];
            __syncthreads();
        }
    } else {
        // fallback: direct racy scatter (R12 semantics, grid-stride)
        int nq = n_pts >> 2;
        for (int q = blockIdx.x * 256 + threadIdx.x; q < nq;
             q += gridDim.x * 256) {
            int i4 = q * 4;
            int b = i4 / HW;
            int r = i4 - b * HW;
            const float* pcb = pc + (size_t)b * 3u * (size_t)HW;
            float4 lab = *(const float4*)(labels + (size_t)b * (size_t)HW + r);
            float4 x0  = *(const float4*)(pcb + r);
            float4 z0  = *(const float4*)(pcb + 2 * (size_t)HW + r);
            float* outb = out + (size_t)b * (size_t)img;
            float xs[4] = {x0.x, x0.y, x0.z, x0.w};
            float zs[4] = {z0.x, z0.y, z0.z, z0.w};
            float ls[4] = {lab.x, lab.y, lab.z, lab.w};
#pragma unroll
            for (int k = 0; k < 4; ++k) {
                int xi, zi; classE(xs[k], zs[k], rd, half_w, xi, zi);
                if (xi >= 0 && xi < bev_w && zi >= 0 && zi < bev_h)
                    outb[(size_t)zi * (size_t)bev_w + (size_t)xi] = ls[k];
            }
        }
    }
}

extern "C" void kernel_launch(void* const* d_in, const int* in_sizes, int n_in,
                              void* d_out, int out_size, void* d_ws, size_t ws_size,
                              hipStream_t stream) {
    const float* labels = (const float*)d_in[0];   // (B,1,H,W) f32
    const float* pc     = (const float*)d_in[1];   // (B,3,H,W) f32
    const int* p_bev_h  = (const int*)d_in[2];
    const int* p_bev_w  = (const int*)d_in[3];
    const int* p_scale  = (const int*)d_in[4];
    float* out = (float*)d_out;
    int n_pts = in_sizes[0];

    // ws layout (host-known sizes only): nblkTot from n_pts
    int nblkTot = (n_pts + P1_PTS - 1) / P1_PTS;
    size_t cell_bytes = (size_t)nblkTot * P1_PTS * 2;
    size_t lab_bytes  = (size_t)nblkTot * P1_PTS * 4;
    size_t off_bytes  = (size_t)nblkTot * OFF_STRIDE * 2;
    size_t need = cell_bytes + lab_bytes + off_bytes;
    int ws_ok = (ws_size >= need) ? 1 : 0;

    u16*  cell16 = (u16*)d_ws;
    float* lab32 = (float*)((char*)d_ws + cell_bytes);
    u16*  offs16 = (u16*)((char*)d_ws + cell_bytes + lab_bytes);

    // kA: P1 (bin) or fallback fill. Grid covers both roles.
    int ka_blocks = nblkTot > 2048 ? nblkTot : 2048;
    kA<<<ka_blocks, 256, 0, stream>>>(labels, pc, p_bev_h, p_bev_w, p_scale,
                                      out, cell16, lab32, offs16,
                                      n_pts, out_size, ws_ok);

    // kB: P2 (tile assemble+write) or fallback scatter. Grid-stride inside.
    kB<<<2048, 256, 0, stream>>>(labels, pc, p_bev_h, p_bev_w, p_scale,
                                 out, cell16, lab32, offs16,
                                 n_pts, out_size, ws_ok);
}

// Round 19
// 48.511 us; speedup vs baseline: 1.1116x; 1.1116x over previous
//
#include <hip/hip_runtime.h>
#include <hip/hip_bf16.h>

typedef unsigned short u16;
typedef unsigned int   u32;

#define P1_PTS    1024
#define BAND_ROWS 16
#define NB_MAX    64
#define REG_MAX   1024          // max (batch,band) regions
#define CAP       32768         // pairs per region (avg ~2K here; max band ~8K)
#define OVF_CAP   65536

// ws layout (bytes):
#define OVFC_WORD (REG_MAX)                    // word index of ovf counter
#define OVF_OFF   ((REG_MAX + 64) * 4)         // uint2[OVF_CAP]
#define CELL_OFF  (1u << 20)                   // u16 [REG_MAX*CAP]  = 64 MiB
#define LAB_OFF   (CELL_OFF + (size_t)REG_MAX * CAP * 2)  // f32, 128 MiB

__device__ __forceinline__ bool fit_ok(int HW, int bev_h, int bev_w, int B,
                                       int ws_ok) {
    int nb = bev_h / BAND_ROWS;
    return ws_ok && (HW % P1_PTS == 0) && (bev_h % BAND_ROWS == 0) &&
           (nb <= NB_MAX) && (B * nb <= REG_MAX) && (bev_w <= 1024) &&
           (bev_w % 4 == 0);
}

// Class-E index math (verified R11): single f32 rounding of the EXACT
// quotient a/(0.1*scale) via opaque f64 reciprocal-multiply; f32 add of
// bev_w/2, rintf (RNE), trunc-to-int.
__device__ __forceinline__ void classE(float px, float pz, double rd,
                                       float half_w, int& xi, int& zi) {
    float xq = (float)((double)(-px) * rd);
    float zq = (float)((double)pz  * rd);
    xi = (int)rintf(__fadd_rn(xq, half_w));
    zi = (int)rintf(zq);
}

// K0: zero region counters + overflow counter.
__global__ void k0(u32* __restrict__ ws) {
    for (int i = threadIdx.x; i < REG_MAX + 64; i += 256) ws[i] = 0u;
}

// kA / P1: per-block LDS counting sort into z-bands; ONE global atomicAdd per
// (block,band) reserves a contiguous range in the (batch,band) slice; runs
// written coalesced. Fallback (!fit): EMPTY fill.
__global__ __launch_bounds__(256) void kA(const float* __restrict__ labels,
        const float* __restrict__ pc,
        const int* __restrict__ p_bev_h, const int* __restrict__ p_bev_w,
        const int* __restrict__ p_scale, float* __restrict__ out,
        u32* __restrict__ ws, int n_pts, int out_size, int ws_ok) {
    const int bev_h = *p_bev_h, bev_w = *p_bev_w, scale = *p_scale;
    const int img = bev_h * bev_w;
    const int B = out_size / img;
    const int HW = n_pts / B;
    const float half_w = (float)(bev_w / 2);
    double rd = 1.0 / (0.1 * (double)scale);
    asm volatile("" : "+v"(rd));

    if (fit_ok(HW, bev_h, bev_w, B, ws_ok)) {
        const int nb = bev_h / BAND_ROWS;
        const int nblk_pb = HW / P1_PTS;
        const int nblkTot = B * nblk_pb;
        if ((int)blockIdx.x >= nblkTot) return;
        const int batch = blockIdx.x / nblk_pb;
        const int tid = threadIdx.x;
        const int r = (blockIdx.x - batch * nblk_pb) * P1_PTS + tid * 4;

        u32* cnt = ws;
        u16* cell16 = (u16*)((char*)ws + CELL_OFF);
        float* lab32 = (float*)((char*)ws + LAB_OFF);
        u32* ovfc = ws + OVFC_WORD;
        uint2* ovf = (uint2*)((char*)ws + OVF_OFF);

        __shared__ u32 hist[NB_MAX], lstart[NB_MAX], cursor[NB_MAX], gb[NB_MAX];
        __shared__ u32 scan[256];
        __shared__ u16 cellL[P1_PTS];
        __shared__ float labL[P1_PTS];
        __shared__ unsigned char bandL[P1_PTS];

        const float* pcb = pc + (size_t)batch * 3u * (size_t)HW;
        float4 lab = *(const float4*)(labels + (size_t)batch * (size_t)HW + r);
        float4 x0  = *(const float4*)(pcb + r);
        float4 z0  = *(const float4*)(pcb + 2 * (size_t)HW + r);
        float xs[4] = {x0.x, x0.y, x0.z, x0.w};
        float zs[4] = {z0.x, z0.y, z0.z, z0.w};
        float ls[4] = {lab.x, lab.y, lab.z, lab.w};

        int band[4]; u16 cell[4]; bool val[4];
#pragma unroll
        for (int k = 0; k < 4; ++k) {
            int xi, zi; classE(xs[k], zs[k], rd, half_w, xi, zi);
            val[k]  = (xi >= 0 && xi < bev_w && zi >= 0 && zi < bev_h);
            band[k] = val[k] ? (zi / BAND_ROWS) : 0;
            cell[k] = val[k] ? (u16)((zi & (BAND_ROWS - 1)) * bev_w + xi) : 0;
        }
        if (tid < nb) hist[tid] = 0;
        __syncthreads();
#pragma unroll
        for (int k = 0; k < 4; ++k) if (val[k]) atomicAdd(&hist[band[k]], 1u);
        __syncthreads();
        u32 v = (tid < nb) ? hist[tid] : 0;
        scan[tid] = v;
        __syncthreads();
        for (int d = 1; d < NB_MAX; d <<= 1) {
            u32 t = (tid >= d) ? scan[tid - d] : 0;
            __syncthreads();
            scan[tid] += t;
            __syncthreads();
        }
        if (tid < nb) {
            lstart[tid] = tid ? scan[tid - 1] : 0;
            cursor[tid] = lstart[tid];
            gb[tid] = hist[tid] ? atomicAdd(&cnt[batch * nb + tid], hist[tid]) : 0;
        }
        __syncthreads();
#pragma unroll
        for (int k = 0; k < 4; ++k) if (val[k]) {
            u32 p = atomicAdd(&cursor[band[k]], 1u);
            cellL[p] = cell[k];
            labL[p]  = ls[k];
            bandL[p] = (unsigned char)band[k];
        }
        __syncthreads();
        u32 total = scan[nb - 1];
        for (u32 i = tid; i < total; i += 256) {
            int bnd = bandL[i];
            u32 gp = gb[bnd] + (i - lstart[bnd]);
            if (gp < CAP) {
                size_t s = (size_t)(batch * nb + bnd) * CAP + gp;
                cell16[s] = cellL[i];
                lab32[s]  = labL[i];
            } else {
                u32 op = atomicAdd(ovfc, 1u);
                if (op < OVF_CAP)
                    ovf[op] = make_uint2(
                        (u32)((size_t)batch * img +
                              (size_t)bnd * BAND_ROWS * bev_w + cellL[i]),
                        __float_as_uint(labL[i]));
            }
        }
    } else {
        int n4 = out_size >> 2;
        const float4 vv = make_float4(255.f, 255.f, 255.f, 255.f);
        for (int i = blockIdx.x * 256 + threadIdx.x; i < n4;
             i += gridDim.x * 256)
            ((float4*)out)[i] = vv;
    }
}

// kB / P2: one block per (batch,band): coalesced slice read, LDS-tile
// scatter, coalesced float4 streamout (absorbs the fill). Fallback (!fit):
// direct racy scatter (R12 champion form).
__global__ __launch_bounds__(256) void kB(const float* __restrict__ labels,
        const float* __restrict__ pc,
        const int* __restrict__ p_bev_h, const int* __restrict__ p_bev_w,
        const int* __restrict__ p_scale, float* __restrict__ out,
        u32* __restrict__ ws, int n_pts, int out_size, int ws_ok) {
    const int bev_h = *p_bev_h, bev_w = *p_bev_w, scale = *p_scale;
    const int img = bev_h * bev_w;
    const int B = out_size / img;
    const int HW = n_pts / B;
    const float half_w = (float)(bev_w / 2);
    double rd = 1.0 / (0.1 * (double)scale);
    asm volatile("" : "+v"(rd));

    if (fit_ok(HW, bev_h, bev_w, B, ws_ok)) {
        const int nb = bev_h / BAND_ROWS;
        const int ntiles = B * nb;
        const int nel = BAND_ROWS * bev_w;
        const u32* cnt = ws;
        const u16* cell16 = (const u16*)((const char*)ws + CELL_OFF);
        const float* lab32 = (const float*)((const char*)ws + LAB_OFF);
        __shared__ float tile[BAND_ROWS * 1024];   // 64 KB

        for (int t = blockIdx.x; t < ntiles; t += gridDim.x) {
            int batch = t / nb, band = t - batch * nb;
            for (int i = threadIdx.x; i < nel; i += 256) tile[i] = 255.0f;
            __syncthreads();
            u32 n = cnt[t]; if (n > CAP) n = CAP;
            size_t base = (size_t)t * CAP;
            for (u32 i = threadIdx.x; i < n; i += 256)
                tile[cell16[base + i]] = lab32[base + i];
            __syncthreads();
            float4* dst = (float4*)(out + (size_t)batch * img +
                                    (size_t)band * nel);
            const float4* src = (const float4*)tile;
            for (int i = threadIdx.x; i < (nel >> 2); i += 256) dst[i] = src[i];
            __syncthreads();
        }
    } else {
        int nq = n_pts >> 2;
        for (int q = blockIdx.x * 256 + threadIdx.x; q < nq;
             q += gridDim.x * 256) {
            int i4 = q * 4;
            int b = i4 / HW;
            int r = i4 - b * HW;
            const float* pcb = pc + (size_t)b * 3u * (size_t)HW;
            float4 lab = *(const float4*)(labels + (size_t)b * (size_t)HW + r);
            float4 x0  = *(const float4*)(pcb + r);
            float4 z0  = *(const float4*)(pcb + 2 * (size_t)HW + r);
            float* outb = out + (size_t)b * (size_t)img;
            float xs[4] = {x0.x, x0.y, x0.z, x0.w};
            float zs[4] = {z0.x, z0.y, z0.z, z0.w};
            float ls[4] = {lab.x, lab.y, lab.z, lab.w};
#pragma unroll
            for (int k = 0; k < 4; ++k) {
                int xi, zi; classE(xs[k], zs[k], rd, half_w, xi, zi);
                if (xi >= 0 && xi < bev_w && zi >= 0 && zi < bev_h)
                    outb[(size_t)zi * (size_t)bev_w + (size_t)xi] = ls[k];
            }
        }
    }
}

// K3: scatter rare overflow pairs (after K2; ovf_cnt==0 in fallback).
__global__ void k3(const u32* __restrict__ ws, float* __restrict__ out) {
    u32 n = ws[OVFC_WORD];
    if (n > OVF_CAP) n = OVF_CAP;
    const uint2* ovf = (const uint2*)((const char*)ws + OVF_OFF);
    for (u32 i = blockIdx.x * 256 + threadIdx.x; i < n; i += gridDim.x * 256) {
        uint2 p = ovf[i];
        out[p.x] = __uint_as_float(p.y);
    }
}

extern "C" void kernel_launch(void* const* d_in, const int* in_sizes, int n_in,
                              void* d_out, int out_size, void* d_ws, size_t ws_size,
                              hipStream_t stream) {
    const float* labels = (const float*)d_in[0];   // (B,1,H,W) f32
    const float* pc     = (const float*)d_in[1];   // (B,3,H,W) f32
    const int* p_bev_h  = (const int*)d_in[2];
    const int* p_bev_w  = (const int*)d_in[3];
    const int* p_scale  = (const int*)d_in[4];
    float* out = (float*)d_out;
    int n_pts = in_sizes[0];

    size_t need = LAB_OFF + (size_t)REG_MAX * CAP * 4;
    int ws_ok = (ws_size >= need) ? 1 : 0;
    u32* ws = (u32*)d_ws;

    int nblkTot = (n_pts + P1_PTS - 1) / P1_PTS;
    int ka_grid = nblkTot > 2048 ? nblkTot : 2048;

    k0<<<1, 256, 0, stream>>>(ws);
    kA<<<ka_grid, 256, 0, stream>>>(labels, pc, p_bev_h, p_bev_w, p_scale,
                                    out, ws, n_pts, out_size, ws_ok);
    kB<<<2048, 256, 0, stream>>>(labels, pc, p_bev_h, p_bev_w, p_scale,
                                 out, ws, n_pts, out_size, ws_ok);
    k3<<<64, 256, 0, stream>>>(ws, out);
}